// Round 1
// baseline (323.326 us; speedup 1.0000x reference)
//
#include <hip/hip_runtime.h>
#include <math.h>

#define NCLS 80
#define TOPK 1000
#define NWORDS 16          // ceil(1000/64)
#define CAND_CAP 4096

// Correctly-rounded float sigmoid: matches numpy's 1/(1+np.exp(-x)) bit-for-bit
// (double exp rounded to float == correctly-rounded float exp, up to double-rounding ~1e-9 prob).
__device__ __forceinline__ float sigmoid_np(float x) {
  float e = (float)exp(-(double)x);
  return 1.0f / (1.0f + e);
}
__device__ __forceinline__ float exp_np(float x) { return (float)exp((double)x); }

// monotonic float->uint key (handles sign generally; scores are positive here)
__device__ __forceinline__ unsigned fkey(float s) {
  unsigned u = __float_as_uint(s);
  return ((int)u < 0) ? ~u : (u | 0x80000000u);
}

__global__ void k_score(const float* __restrict__ cls, float* __restrict__ scores,
                        int* __restrict__ labels, unsigned* __restrict__ hist, int M) {
  int i = blockIdx.x * blockDim.x + threadIdx.x;
  if (i >= M) return;
  const float4* row = reinterpret_cast<const float4*>(cls) + (size_t)i * (NCLS / 4);
  float best = -1.0f; int bestc = 0;
  #pragma unroll
  for (int q = 0; q < NCLS / 4; ++q) {
    float4 v = row[q];
    float p;
    p = sigmoid_np(v.x); if (p > best) { best = p; bestc = q * 4 + 0; }
    p = sigmoid_np(v.y); if (p > best) { best = p; bestc = q * 4 + 1; }
    p = sigmoid_np(v.z); if (p > best) { best = p; bestc = q * 4 + 2; }
    p = sigmoid_np(v.w); if (p > best) { best = p; bestc = q * 4 + 3; }
  }
  scores[i] = best;
  labels[i] = bestc;
  atomicAdd(&hist[fkey(best) >> 16], 1u);
}

__launch_bounds__(1024)
__global__ void k_select(const unsigned* __restrict__ hist, const float* __restrict__ scores,
                         const int* __restrict__ labels, const float* __restrict__ reg,
                         const float* __restrict__ asz, const int* __restrict__ pW,
                         int M, int A,
                         float* __restrict__ sel_score, int* __restrict__ sel_label,
                         float* __restrict__ boxes, float* __restrict__ areas,
                         float* __restrict__ obox) {
  __shared__ unsigned chunks[1024];
  __shared__ int sB;
  __shared__ unsigned scnt;
  __shared__ unsigned long long cand[CAND_CAP];
  const int t = threadIdx.x;

  // chunk sums over 64 buckets each (65536 buckets total)
  unsigned s = 0;
  const int base = t * 64;
  for (int b = 0; b < 64; ++b) s += hist[base + b];
  chunks[t] = s;
  __syncthreads();
  // inclusive suffix sum (Hillis-Steele)
  for (int d = 1; d < 1024; d <<= 1) {
    unsigned v = chunks[t] + ((t + d < 1024) ? chunks[t + d] : 0u);
    __syncthreads();
    chunks[t] = v;
    __syncthreads();
  }
  unsigned ssc = chunks[t];
  unsigned ssn = (t + 1 < 1024) ? chunks[t + 1] : 0u;
  if (ssc >= (unsigned)TOPK && ssn < (unsigned)TOPK) {
    unsigned run = ssn; int B = base;
    for (int b = 63; b >= 0; --b) {
      run += hist[base + b];
      if (run >= (unsigned)TOPK) { B = base + b; break; }
    }
    sB = B;
  }
  if (t == 0) scnt = 0;
  __syncthreads();
  const unsigned Bb = (unsigned)sB;

  // compact candidates with bucket >= B into LDS, key = (score_key<<32)|~idx
  for (int i = t; i < M; i += 1024) {
    unsigned key = fkey(scores[i]);
    if ((key >> 16) >= Bb) {
      unsigned p = atomicAdd(&scnt, 1u);
      if (p < (unsigned)CAND_CAP)
        cand[p] = ((unsigned long long)key << 32) | (unsigned)(~(unsigned)i);
    }
  }
  __syncthreads();
  unsigned n = scnt; if (n > (unsigned)CAND_CAP) n = (unsigned)CAND_CAP;
  for (int i = t; i < CAND_CAP; i += 1024) if ((unsigned)i >= n) cand[i] = 0ull;
  __syncthreads();

  // bitonic sort, descending
  for (int k = 2; k <= CAND_CAP; k <<= 1) {
    for (int j = k >> 1; j > 0; j >>= 1) {
      for (int i = t; i < CAND_CAP; i += 1024) {
        int ij = i ^ j;
        if (ij > i) {
          unsigned long long a = cand[i], b = cand[ij];
          bool up = (i & k) == 0;
          if ((a < b) == up) { cand[i] = b; cand[ij] = a; }
        }
      }
      __syncthreads();
    }
  }

  // decode top-1000
  if (t < TOPK) {
    unsigned long long kk = cand[t];
    unsigned key = (unsigned)(kk >> 32);
    unsigned u = (key & 0x80000000u) ? (key ^ 0x80000000u) : ~key;
    float sc = __uint_as_float(u);
    int idx = (int)(~(unsigned)kk);
    int lab = labels[idx];
    int W = *pW;
    int a = idx % A;
    int cell = idx / A;
    int x = cell % W;
    int y = cell / W;
    float aw = asz[a * 2 + 0], ah = asz[a * 2 + 1];
    float ax = ((float)x + 0.5f) * 32.0f;
    float ay = ((float)y + 0.5f) * 32.0f;
    float4 rg = *reinterpret_cast<const float4*>(reg + (size_t)idx * 4);
    float offx = fminf(fmaxf(rg.x * aw, -32.0f), 32.0f);
    float offy = fminf(fmaxf(rg.y * ah, -32.0f), 32.0f);
    float cx = ax + offx, cy = ay + offy;
    const float SC = 4.135166556742356f;  // log(1000/16) rounded to f32
    float bw = aw * exp_np(fminf(rg.z, SC));
    float bh = ah * exp_np(fminf(rg.w, SC));
    float x1 = cx - 0.5f * bw, y1 = cy - 0.5f * bh;
    float x2 = cx + 0.5f * bw, y2 = cy + 0.5f * bh;
    float off = (float)lab * 100000.0f;
    float ox1 = x1 + off, oy1 = y1 + off, ox2 = x2 + off, oy2 = y2 + off;
    sel_score[t] = sc; sel_label[t] = lab;
    boxes[t * 4 + 0] = x1; boxes[t * 4 + 1] = y1;
    boxes[t * 4 + 2] = x2; boxes[t * 4 + 3] = y2;
    obox[0 * 1024 + t] = ox1; obox[1 * 1024 + t] = oy1;
    obox[2 * 1024 + t] = ox2; obox[3 * 1024 + t] = oy2;
    areas[t] = (ox2 - ox1) * (oy2 - oy1);  // areas on offset boxes, like the reference
  }
}

__global__ void k_mask(const float* __restrict__ obox, const float* __restrict__ areas,
                       unsigned long long* __restrict__ mask) {
  int task = blockIdx.x * blockDim.x + threadIdx.x;
  if (task >= TOPK * NWORDS) return;
  int i = task >> 4, w = task & 15;
  float x1i = obox[i], y1i = obox[1024 + i], x2i = obox[2048 + i], y2i = obox[3072 + i];
  float ai = areas[i];
  unsigned long long bits = 0ull;
  int j0 = w * 64;
  for (int jj = 0; jj < 64; ++jj) {
    int j = j0 + jj;
    if (j >= TOPK) break;
    if (j <= i) continue;
    float xx1 = fmaxf(x1i, obox[j]);
    float yy1 = fmaxf(y1i, obox[1024 + j]);
    float xx2 = fminf(x2i, obox[2048 + j]);
    float yy2 = fminf(y2i, obox[3072 + j]);
    float inter = fmaxf(1e-28f, xx2 - xx1) * fmaxf(1e-28f, yy2 - yy1);
    float uni = ai + areas[j] - inter + 1e-14f;
    float iou = inter / uni;            // IEEE division: bit-matches the reference
    if (iou > 0.6f) bits |= (1ull << jj);
  }
  mask[i * NWORDS + w] = bits;
}

__device__ __forceinline__ unsigned long long shfl64(unsigned long long v, int src) {
  unsigned lo = (unsigned)__shfl((int)(unsigned)(v & 0xffffffffull), src, 64);
  unsigned hi = (unsigned)__shfl((int)(unsigned)(v >> 32), src, 64);
  return ((unsigned long long)hi << 32) | lo;
}

__launch_bounds__(1024)
__global__ void k_nms_out(const unsigned long long* __restrict__ maskG,
                          const float* __restrict__ sel_score, const int* __restrict__ sel_label,
                          const float* __restrict__ boxes,
                          const int* __restrict__ pW, const int* __restrict__ pH,
                          float* __restrict__ out) {
  __shared__ unsigned long long maskL[TOPK * NWORDS];
  __shared__ unsigned long long validw[NWORDS];
  __shared__ unsigned long long keepw[NWORDS];
  const int t = threadIdx.x;
  for (int i = t; i < TOPK * NWORDS; i += 1024) maskL[i] = maskG[i];
  if (t < NWORDS) {
    unsigned long long v = 0ull;
    for (int b = 0; b < 64; ++b) {
      int r = t * 64 + b;
      if (r < TOPK && sel_score[r] >= 0.05f) v |= (1ull << b);
    }
    validw[t] = v;
  }
  __syncthreads();

  if (t < 64) {  // wave 0: serial greedy over the suppression bitmask
    const int lane = t;
    unsigned long long supp = 0ull, kw = 0ull;
    unsigned long long vl = (lane < NWORDS) ? validw[lane] : 0ull;
    unsigned long long cur_supp = 0ull, cur_valid = 0ull;
    unsigned long long bufA[8], bufB[8];
    #pragma unroll
    for (int k = 0; k < 8; ++k)
      bufA[k] = (lane < NWORDS) ? maskL[k * NWORDS + lane] : 0ull;
    for (int g = 0; g < TOPK / 8; ++g) {
      #pragma unroll
      for (int k = 0; k < 8; ++k)
        bufB[k] = (lane < NWORDS && g + 1 < TOPK / 8)
                    ? maskL[((g + 1) * 8 + k) * NWORDS + lane] : 0ull;
      #pragma unroll
      for (int k = 0; k < 8; ++k) {
        int i = g * 8 + k;
        int wi = i >> 6, bit = i & 63;
        if (bit == 0) { cur_supp = shfl64(supp, wi); cur_valid = shfl64(vl, wi); }
        unsigned long long bm = shfl64(bufA[k], wi);  // off the dependent chain
        bool kept = ((cur_valid >> bit) & 1ull) && !((cur_supp >> bit) & 1ull);
        if (kept) {
          cur_supp |= bm;
          supp |= bufA[k];
          if (lane == wi) kw |= (1ull << bit);
        }
      }
      #pragma unroll
      for (int k = 0; k < 8; ++k) bufA[k] = bufB[k];
    }
    if (lane < NWORDS) keepw[lane] = kw;
  }
  __syncthreads();

  if (t < TOPK) {
    bool kp = (keepw[t >> 6] >> (t & 63)) & 1ull;
    float m = kp ? 1.0f : 0.0f;
    float sw = (float)(*pW * 32);
    float sh = (float)(*pH * 32);
    float b0 = boxes[t * 4 + 0] / sw;
    float b1 = boxes[t * 4 + 1] / sh;
    float b2 = boxes[t * 4 + 2] / sw;
    float b3 = boxes[t * 4 + 3] / sh;
    b0 = fminf(fmaxf(b0, 0.0f), 1.0f) * m;
    b1 = fminf(fmaxf(b1, 0.0f), 1.0f) * m;
    b2 = fminf(fmaxf(b2, 0.0f), 1.0f) * m;
    b3 = fminf(fmaxf(b3, 0.0f), 1.0f) * m;
    out[t * 4 + 0] = b0; out[t * 4 + 1] = b1;
    out[t * 4 + 2] = b2; out[t * 4 + 3] = b3;
    out[TOPK * 4 + t] = sel_score[t] * m;
    out[TOPK * 5 + t] = kp ? (float)sel_label[t] : -1.0f;
    out[TOPK * 6 + t] = m;
  }
}

extern "C" void kernel_launch(void* const* d_in, const int* in_sizes, int n_in,
                              void* d_out, int out_size, void* d_ws, size_t ws_size,
                              hipStream_t stream) {
  const float* cls = (const float*)d_in[0];
  const float* reg = (const float*)d_in[1];
  const float* asz = (const float*)d_in[2];
  const int* pH = (const int*)d_in[3];
  const int* pW = (const int*)d_in[4];
  int M = in_sizes[0] / NCLS;
  int A = in_sizes[2] / 2;

  char* ws = (char*)d_ws;
  size_t off = 0;
  auto alloc = [&](size_t bytes) { size_t o = off; off = (off + bytes + 255) & ~(size_t)255; return o; };
  size_t o_hist  = alloc(65536 * sizeof(unsigned));
  size_t o_sc    = alloc((size_t)M * sizeof(float));
  size_t o_lb    = alloc((size_t)M * sizeof(int));
  size_t o_ssc   = alloc(1024 * sizeof(float));
  size_t o_slb   = alloc(1024 * sizeof(int));
  size_t o_box   = alloc((size_t)TOPK * 4 * sizeof(float));
  size_t o_area  = alloc(1024 * sizeof(float));
  size_t o_obox  = alloc(4 * 1024 * sizeof(float));
  size_t o_mask  = alloc((size_t)TOPK * NWORDS * sizeof(unsigned long long));
  (void)ws_size; (void)out_size; (void)n_in;

  hipMemsetAsync(ws + o_hist, 0, 65536 * sizeof(unsigned), stream);
  k_score<<<(M + 255) / 256, 256, 0, stream>>>(
      cls, (float*)(ws + o_sc), (int*)(ws + o_lb), (unsigned*)(ws + o_hist), M);
  k_select<<<1, 1024, 0, stream>>>(
      (const unsigned*)(ws + o_hist), (const float*)(ws + o_sc), (const int*)(ws + o_lb),
      reg, asz, pW, M, A,
      (float*)(ws + o_ssc), (int*)(ws + o_slb),
      (float*)(ws + o_box), (float*)(ws + o_area), (float*)(ws + o_obox));
  k_mask<<<(TOPK * NWORDS + 255) / 256, 256, 0, stream>>>(
      (const float*)(ws + o_obox), (const float*)(ws + o_area),
      (unsigned long long*)(ws + o_mask));
  k_nms_out<<<1, 1024, 0, stream>>>(
      (const unsigned long long*)(ws + o_mask),
      (const float*)(ws + o_ssc), (const int*)(ws + o_slb),
      (const float*)(ws + o_box), pW, pH, (float*)d_out);
}

// Round 2
// 297.006 us; speedup vs baseline: 1.0886x; 1.0886x over previous
//
#include <hip/hip_runtime.h>
#include <math.h>

#define NCLS 80
#define TOPK 1000
#define NWORDS 16          // ceil(1000/64)
#define CAND_CAP 2048

// Correctly-rounded float sigmoid: matches numpy's 1/(1+np.exp(-x)) bit-for-bit.
__device__ __forceinline__ float sigmoid_np(float x) {
  float e = (float)exp(-(double)x);
  return 1.0f / (1.0f + e);
}
__device__ __forceinline__ float exp_np(float x) { return (float)exp((double)x); }

// monotonic float->uint key
__device__ __forceinline__ unsigned fkey(float s) {
  unsigned u = __float_as_uint(s);
  return ((int)u < 0) ? ~u : (u | 0x80000000u);
}

// 4 lanes per anchor; max/argmax on raw logits (sigmoid is monotonic),
// one exact sigmoid per anchor; guarded exact fallback for rounded-sigmoid ties.
__global__ void k_score(const float* __restrict__ cls, float* __restrict__ scores,
                        int* __restrict__ labels, unsigned* __restrict__ hist, int M) {
  int gid = blockIdx.x * blockDim.x + threadIdx.x;
  int anchor = gid >> 2;
  int q = gid & 3;
  if (anchor >= M) return;
  const float4* row = reinterpret_cast<const float4*>(cls) + (size_t)anchor * (NCLS / 4);
  float lv[20];
  float best = -3.4e38f; int bc = 0;
  #pragma unroll
  for (int k = 0; k < 5; ++k) {
    float4 v = row[q + 4 * k];          // coalesced: lanes 0..3 hit consecutive 16B
    int cbase = (q + 4 * k) * 4;
    lv[4 * k + 0] = v.x; lv[4 * k + 1] = v.y; lv[4 * k + 2] = v.z; lv[4 * k + 3] = v.w;
    if (v.x > best) { best = v.x; bc = cbase + 0; }
    if (v.y > best) { best = v.y; bc = cbase + 1; }
    if (v.z > best) { best = v.z; bc = cbase + 2; }
    if (v.w > best) { best = v.w; bc = cbase + 3; }
  }
  // reduce (max, first-index) across the anchor's 4 lanes
  #pragma unroll
  for (int d = 1; d < 4; d <<= 1) {
    float ob = __shfl_xor(best, d, 64);
    int oc = __shfl_xor(bc, d, 64);
    if (ob > best || (ob == best && oc < bc)) { best = ob; bc = oc; }
  }
  float s = sigmoid_np(best);
  // collision band: logit gap below this can round to the same float sigmoid
  float sp = s * (1.0f - s);
  float band = (s < 1.0f && sp > 0.0f) ? (4.8e-7f / sp) : 3.4e38f;  // 8 ulps margin
  float thresh = best - band;
  int cclose = 1 << 30;
  #pragma unroll
  for (int k = 0; k < 5; ++k) {
    #pragma unroll
    for (int j = 0; j < 4; ++j) {
      int c = (q + 4 * k) * 4 + j;
      if (lv[4 * k + j] >= thresh && c < cclose) cclose = c;
    }
  }
  #pragma unroll
  for (int d = 1; d < 4; d <<= 1) {
    int oc = __shfl_xor(cclose, d, 64);
    if (oc < cclose) cclose = oc;
  }
  int lab = bc;
  if (cclose < bc && q == 0) {  // rare: exact serial argmax over rounded sigmoids
    float bp = -1.0f; int bl = 0;
    for (int c = 0; c < NCLS; ++c) {
      float p = sigmoid_np(cls[(size_t)anchor * NCLS + c]);
      if (p > bp) { bp = p; bl = c; }
    }
    lab = bl;
  }
  if (q == 0) {
    scores[anchor] = s;
    labels[anchor] = lab;
    atomicAdd(&hist[fkey(s) >> 16], 1u);
  }
}

__launch_bounds__(1024)
__global__ void k_select(const unsigned* __restrict__ hist, const float* __restrict__ scores,
                         const int* __restrict__ labels, const float* __restrict__ reg,
                         const float* __restrict__ asz, const int* __restrict__ pW,
                         int M, int A,
                         float* __restrict__ sel_score, int* __restrict__ sel_label,
                         float* __restrict__ boxes, float* __restrict__ areas,
                         float* __restrict__ obox) {
  __shared__ unsigned chunks[1024];
  __shared__ unsigned hist2[4096];
  __shared__ unsigned long long cand[CAND_CAP];
  __shared__ int sB, sF;
  __shared__ unsigned sAbove, scnt;
  const int t = threadIdx.x;

  // ---- Phase A: coarse threshold bucket B over 16-bit key prefix ----
  #pragma unroll
  for (int k = 0; k < 4; ++k) hist2[t + 1024 * k] = 0u;
  unsigned s = 0;
  const int base = t * 64;
  for (int b = 0; b < 64; ++b) s += hist[base + b];
  chunks[t] = s;
  __syncthreads();
  for (int d = 1; d < 1024; d <<= 1) {   // inclusive suffix sum
    unsigned v = chunks[t] + ((t + d < 1024) ? chunks[t + d] : 0u);
    __syncthreads();
    chunks[t] = v;
    __syncthreads();
  }
  {
    unsigned ssc = chunks[t];
    unsigned ssn = (t + 1 < 1024) ? chunks[t + 1] : 0u;
    if (ssc >= (unsigned)TOPK && ssn < (unsigned)TOPK) {
      unsigned run = ssn;
      for (int b = 63; b >= 0; --b) {
        unsigned h = hist[base + b];
        run += h;
        if (run >= (unsigned)TOPK) { sB = base + b; sAbove = run - h; break; }
      }
    }
  }
  if (t == 0) scnt = 0u;
  __syncthreads();
  const unsigned B = (unsigned)sB;
  const unsigned nAbove = sAbove;

  // ---- Phase B: fine histogram of bucket B on key bits [15:4] ----
  for (int i = t; i < M; i += 1024) {
    unsigned key = fkey(scores[i]);
    if ((key >> 16) == B) atomicAdd(&hist2[(key >> 4) & 0xFFFu], 1u);
  }
  __syncthreads();

  // ---- Phase C: fine threshold F ----
  {
    unsigned c4 = hist2[4 * t] + hist2[4 * t + 1] + hist2[4 * t + 2] + hist2[4 * t + 3];
    chunks[t] = c4;
  }
  __syncthreads();
  for (int d = 1; d < 1024; d <<= 1) {
    unsigned v = chunks[t] + ((t + d < 1024) ? chunks[t + d] : 0u);
    __syncthreads();
    chunks[t] = v;
    __syncthreads();
  }
  {
    unsigned ssc = nAbove + chunks[t];
    unsigned ssn = nAbove + ((t + 1 < 1024) ? chunks[t + 1] : 0u);
    if (ssc >= (unsigned)TOPK && ssn < (unsigned)TOPK) {
      unsigned run = ssn;
      for (int b = 3; b >= 0; --b) {
        run += hist2[4 * t + b];
        if (run >= (unsigned)TOPK) { sF = 4 * t + b; break; }
      }
    }
  }
  __syncthreads();
  const unsigned F = (unsigned)sF;

  // ---- Phase D: compact candidates, key = (score_key<<32) | ~idx ----
  for (int i = t; i < M; i += 1024) {
    unsigned key = fkey(scores[i]);
    unsigned pr = key >> 16;
    if (pr > B || (pr == B && ((key >> 4) & 0xFFFu) >= F)) {
      unsigned p = atomicAdd(&scnt, 1u);
      if (p < (unsigned)CAND_CAP)
        cand[p] = ((unsigned long long)key << 32) | (unsigned)(~(unsigned)i);
    }
  }
  __syncthreads();
  unsigned n = scnt; if (n > (unsigned)CAND_CAP) n = (unsigned)CAND_CAP;
  for (int i = t; i < CAND_CAP; i += 1024) if ((unsigned)i >= n) cand[i] = 0ull;
  __syncthreads();

  // ---- bitonic sort (descending), 2048 elems, 1 compare/thread/step ----
  for (int k = 2; k <= CAND_CAP; k <<= 1) {
    for (int j = k >> 1; j > 0; j >>= 1) {
      int i = ((t & ~(j - 1)) << 1) | (t & (j - 1));
      int ij = i | j;
      unsigned long long a = cand[i], b = cand[ij];
      bool desc = (i & k) == 0;
      if ((a < b) == desc) { cand[i] = b; cand[ij] = a; }
      __syncthreads();
    }
  }

  // ---- decode top-1000 ----
  if (t < TOPK) {
    unsigned long long kk = cand[t];
    unsigned key = (unsigned)(kk >> 32);
    unsigned u = (key & 0x80000000u) ? (key ^ 0x80000000u) : ~key;
    float sc = __uint_as_float(u);
    int idx = (int)(~(unsigned)kk);
    int lab = labels[idx];
    int W = *pW;
    int a = idx % A;
    int cell = idx / A;
    int x = cell % W;
    int y = cell / W;
    float aw = asz[a * 2 + 0], ah = asz[a * 2 + 1];
    float ax = ((float)x + 0.5f) * 32.0f;
    float ay = ((float)y + 0.5f) * 32.0f;
    float4 rg = *reinterpret_cast<const float4*>(reg + (size_t)idx * 4);
    float offx = fminf(fmaxf(rg.x * aw, -32.0f), 32.0f);
    float offy = fminf(fmaxf(rg.y * ah, -32.0f), 32.0f);
    float cx = ax + offx, cy = ay + offy;
    const float SC = 4.135166556742356f;  // log(1000/16)
    float bw = aw * exp_np(fminf(rg.z, SC));
    float bh = ah * exp_np(fminf(rg.w, SC));
    float x1 = cx - 0.5f * bw, y1 = cy - 0.5f * bh;
    float x2 = cx + 0.5f * bw, y2 = cy + 0.5f * bh;
    float off = (float)lab * 100000.0f;
    float ox1 = x1 + off, oy1 = y1 + off, ox2 = x2 + off, oy2 = y2 + off;
    sel_score[t] = sc; sel_label[t] = lab;
    boxes[t * 4 + 0] = x1; boxes[t * 4 + 1] = y1;
    boxes[t * 4 + 2] = x2; boxes[t * 4 + 3] = y2;
    obox[0 * 1024 + t] = ox1; obox[1 * 1024 + t] = oy1;
    obox[2 * 1024 + t] = ox2; obox[3 * 1024 + t] = oy2;
    areas[t] = (ox2 - ox1) * (oy2 - oy1);  // areas on offset boxes, like the reference
  }
}

__global__ void k_mask(const float* __restrict__ obox, const float* __restrict__ areas,
                       unsigned long long* __restrict__ mask) {
  int task = blockIdx.x * blockDim.x + threadIdx.x;
  if (task >= TOPK * NWORDS) return;
  int i = task >> 4, w = task & 15;
  float x1i = obox[i], y1i = obox[1024 + i], x2i = obox[2048 + i], y2i = obox[3072 + i];
  float ai = areas[i];
  unsigned long long bits = 0ull;
  int j0 = w * 64;
  for (int jj = 0; jj < 64; ++jj) {
    int j = j0 + jj;
    if (j >= TOPK) break;
    if (j <= i) continue;
    float xx1 = fmaxf(x1i, obox[j]);
    float yy1 = fmaxf(y1i, obox[1024 + j]);
    float xx2 = fminf(x2i, obox[2048 + j]);
    float yy2 = fminf(y2i, obox[3072 + j]);
    float inter = fmaxf(1e-28f, xx2 - xx1) * fmaxf(1e-28f, yy2 - yy1);
    float uni = ai + areas[j] - inter + 1e-14f;
    float iou = inter / uni;            // IEEE division: bit-matches the reference
    if (iou > 0.6f) bits |= (1ull << jj);
  }
  mask[i * NWORDS + w] = bits;
}

__device__ __forceinline__ unsigned long long shfl64(unsigned long long v, int src) {
  unsigned lo = (unsigned)__shfl((int)(unsigned)(v & 0xffffffffull), src, 64);
  unsigned hi = (unsigned)__shfl((int)(unsigned)(v >> 32), src, 64);
  return ((unsigned long long)hi << 32) | lo;
}

__launch_bounds__(1024)
__global__ void k_nms_out(const unsigned long long* __restrict__ maskG,
                          const float* __restrict__ sel_score, const int* __restrict__ sel_label,
                          const float* __restrict__ boxes,
                          const int* __restrict__ pW, const int* __restrict__ pH,
                          float* __restrict__ out) {
  __shared__ unsigned long long maskL[TOPK * NWORDS];   // 125 KB
  __shared__ unsigned long long validw[NWORDS];
  __shared__ unsigned long long keepw[NWORDS];
  const int t = threadIdx.x;
  for (int i = t; i < TOPK * NWORDS; i += 1024) maskL[i] = maskG[i];
  if (t < NWORDS) {
    unsigned long long v = 0ull;
    for (int b = 0; b < 64; ++b) {
      int r = t * 64 + b;
      if (r < TOPK && sel_score[r] >= 0.05f) v |= (1ull << b);
    }
    validw[t] = v;
  }
  __syncthreads();

  if (t < 64) {  // wave 0: serial greedy; broadcast words come from LDS (prefetched)
    const int lane = t;
    unsigned long long supp = 0ull, kw = 0ull;
    unsigned long long cur_supp = 0ull, cur_valid = 0ull;
    unsigned long long bufA[8], bufW[8], nbufA[8], nbufW[8];
    #pragma unroll
    for (int k = 0; k < 8; ++k) {
      bufA[k] = (lane < NWORDS) ? maskL[k * NWORDS + lane] : 0ull;
      bufW[k] = maskL[k * NWORDS + 0];            // word (k>>6)==0, same-addr broadcast
    }
    for (int g = 0; g < TOPK / 8; ++g) {
      int gn = g + 1;
      #pragma unroll
      for (int k = 0; k < 8; ++k) {
        int i2 = gn * 8 + k;
        bool ok = gn < TOPK / 8;
        nbufA[k] = (ok && lane < NWORDS) ? maskL[i2 * NWORDS + lane] : 0ull;
        nbufW[k] = ok ? maskL[i2 * NWORDS + (i2 >> 6)] : 0ull;
      }
      #pragma unroll
      for (int k = 0; k < 8; ++k) {
        int i = g * 8 + k;
        int wi = i >> 6, bit = i & 63;
        if (bit == 0) { cur_supp = shfl64(supp, wi); cur_valid = validw[wi]; }
        bool kept = ((cur_valid >> bit) & 1ull) && !((cur_supp >> bit) & 1ull);
        if (kept) {
          cur_supp |= bufW[k];      // replicated copy: keeps the chain register-local
          supp |= bufA[k];          // distributed OR (lanes 0..15 matter)
          if (lane == wi) kw |= (1ull << bit);
        }
      }
      #pragma unroll
      for (int k = 0; k < 8; ++k) { bufA[k] = nbufA[k]; bufW[k] = nbufW[k]; }
    }
    if (lane < NWORDS) keepw[lane] = kw;
  }
  __syncthreads();

  if (t < TOPK) {
    bool kp = (keepw[t >> 6] >> (t & 63)) & 1ull;
    float m = kp ? 1.0f : 0.0f;
    float sw = (float)(*pW * 32);
    float sh = (float)(*pH * 32);
    float b0 = boxes[t * 4 + 0] / sw;
    float b1 = boxes[t * 4 + 1] / sh;
    float b2 = boxes[t * 4 + 2] / sw;
    float b3 = boxes[t * 4 + 3] / sh;
    b0 = fminf(fmaxf(b0, 0.0f), 1.0f) * m;
    b1 = fminf(fmaxf(b1, 0.0f), 1.0f) * m;
    b2 = fminf(fmaxf(b2, 0.0f), 1.0f) * m;
    b3 = fminf(fmaxf(b3, 0.0f), 1.0f) * m;
    out[t * 4 + 0] = b0; out[t * 4 + 1] = b1;
    out[t * 4 + 2] = b2; out[t * 4 + 3] = b3;
    out[TOPK * 4 + t] = sel_score[t] * m;
    out[TOPK * 5 + t] = kp ? (float)sel_label[t] : -1.0f;
    out[TOPK * 6 + t] = m;
  }
}

extern "C" void kernel_launch(void* const* d_in, const int* in_sizes, int n_in,
                              void* d_out, int out_size, void* d_ws, size_t ws_size,
                              hipStream_t stream) {
  const float* cls = (const float*)d_in[0];
  const float* reg = (const float*)d_in[1];
  const float* asz = (const float*)d_in[2];
  const int* pH = (const int*)d_in[3];
  const int* pW = (const int*)d_in[4];
  int M = in_sizes[0] / NCLS;
  int A = in_sizes[2] / 2;

  char* ws = (char*)d_ws;
  size_t off = 0;
  auto alloc = [&](size_t bytes) { size_t o = off; off = (off + bytes + 255) & ~(size_t)255; return o; };
  size_t o_hist  = alloc(65536 * sizeof(unsigned));
  size_t o_sc    = alloc((size_t)M * sizeof(float));
  size_t o_lb    = alloc((size_t)M * sizeof(int));
  size_t o_ssc   = alloc(1024 * sizeof(float));
  size_t o_slb   = alloc(1024 * sizeof(int));
  size_t o_box   = alloc((size_t)TOPK * 4 * sizeof(float));
  size_t o_area  = alloc(1024 * sizeof(float));
  size_t o_obox  = alloc(4 * 1024 * sizeof(float));
  size_t o_mask  = alloc((size_t)TOPK * NWORDS * sizeof(unsigned long long));
  (void)ws_size; (void)out_size; (void)n_in;

  hipMemsetAsync(ws + o_hist, 0, 65536 * sizeof(unsigned), stream);
  int nthread = M * 4;
  k_score<<<(nthread + 255) / 256, 256, 0, stream>>>(
      cls, (float*)(ws + o_sc), (int*)(ws + o_lb), (unsigned*)(ws + o_hist), M);
  k_select<<<1, 1024, 0, stream>>>(
      (const unsigned*)(ws + o_hist), (const float*)(ws + o_sc), (const int*)(ws + o_lb),
      reg, asz, pW, M, A,
      (float*)(ws + o_ssc), (int*)(ws + o_slb),
      (float*)(ws + o_box), (float*)(ws + o_area), (float*)(ws + o_obox));
  k_mask<<<(TOPK * NWORDS + 255) / 256, 256, 0, stream>>>(
      (const float*)(ws + o_obox), (const float*)(ws + o_area),
      (unsigned long long*)(ws + o_mask));
  k_nms_out<<<1, 1024, 0, stream>>>(
      (const unsigned long long*)(ws + o_mask),
      (const float*)(ws + o_ssc), (const int*)(ws + o_slb),
      (const float*)(ws + o_box), pW, pH, (float*)d_out);
}

// Round 3
// 242.537 us; speedup vs baseline: 1.3331x; 1.2246x over previous
//
#include <hip/hip_runtime.h>
#include <math.h>

#define NCLS 80
#define TOPK 1000
#define NWORDS 16          // ceil(1000/64)
#define CAND_CAP 2048

// Correctly-rounded float sigmoid: matches numpy's 1/(1+np.exp(-x)) bit-for-bit.
__device__ __forceinline__ float sigmoid_np(float x) {
  float e = (float)exp(-(double)x);
  return 1.0f / (1.0f + e);
}
__device__ __forceinline__ float exp_np(float x) { return (float)exp((double)x); }

// monotonic float->uint key
__device__ __forceinline__ unsigned fkey(float s) {
  unsigned u = __float_as_uint(s);
  return ((int)u < 0) ? ~u : (u | 0x80000000u);
}

// Wave-aggregated LDS histogram add: one atomic per distinct bin per wave.
__device__ __forceinline__ void agg_add(unsigned* h, unsigned bin, bool pred) {
  unsigned long long rem = __ballot(pred);
  const int lane = threadIdx.x & 63;
  while (rem) {
    int leader = __ffsll(rem) - 1;
    unsigned lb = (unsigned)__shfl((int)bin, leader, 64);
    unsigned long long m = __ballot(pred && bin == lb);
    if (lane == leader) atomicAdd(&h[lb], (unsigned)__popcll(m));
    rem &= ~m;
  }
}

// 4 lanes per anchor; max/argmax on raw logits (sigmoid is monotonic),
// one exact sigmoid per anchor; guarded exact fallback for rounded-sigmoid ties.
// NO atomics — pure streaming.
__global__ void k_score(const float* __restrict__ cls, float* __restrict__ scores,
                        int* __restrict__ labels, int M) {
  int gid = blockIdx.x * blockDim.x + threadIdx.x;
  int anchor = gid >> 2;
  int q = gid & 3;
  if (anchor >= M) return;
  const float4* row = reinterpret_cast<const float4*>(cls) + (size_t)anchor * (NCLS / 4);
  float lv[20];
  float best = -3.4e38f; int bc = 0;
  #pragma unroll
  for (int k = 0; k < 5; ++k) {
    float4 v = row[q + 4 * k];          // lanes 0..3 cover 64B contiguous
    int cbase = (q + 4 * k) * 4;
    lv[4 * k + 0] = v.x; lv[4 * k + 1] = v.y; lv[4 * k + 2] = v.z; lv[4 * k + 3] = v.w;
    if (v.x > best) { best = v.x; bc = cbase + 0; }
    if (v.y > best) { best = v.y; bc = cbase + 1; }
    if (v.z > best) { best = v.z; bc = cbase + 2; }
    if (v.w > best) { best = v.w; bc = cbase + 3; }
  }
  #pragma unroll
  for (int d = 1; d < 4; d <<= 1) {
    float ob = __shfl_xor(best, d, 64);
    int oc = __shfl_xor(bc, d, 64);
    if (ob > best || (ob == best && oc < bc)) { best = ob; bc = oc; }
  }
  float s = sigmoid_np(best);
  // collision band: logit gap below this can round to the same float sigmoid
  float sp = s * (1.0f - s);
  float band = (s < 1.0f && sp > 0.0f) ? (4.8e-7f / sp) : 3.4e38f;  // 8 ulps margin
  float thresh = best - band;
  int cclose = 1 << 30;
  #pragma unroll
  for (int k = 0; k < 5; ++k) {
    #pragma unroll
    for (int j = 0; j < 4; ++j) {
      int c = (q + 4 * k) * 4 + j;
      if (lv[4 * k + j] >= thresh && c < cclose) cclose = c;
    }
  }
  #pragma unroll
  for (int d = 1; d < 4; d <<= 1) {
    int oc = __shfl_xor(cclose, d, 64);
    if (oc < cclose) cclose = oc;
  }
  int lab = bc;
  if (cclose < bc && q == 0) {  // rare: exact serial argmax over rounded sigmoids
    float bp = -1.0f; int bl = 0;
    for (int c = 0; c < NCLS; ++c) {
      float p = sigmoid_np(cls[(size_t)anchor * NCLS + c]);
      if (p > bp) { bp = p; bl = c; }
    }
    lab = bl;
  }
  if (q == 0) {
    scores[anchor] = s;
    labels[anchor] = lab;
  }
}

__launch_bounds__(1024)
__global__ void k_select(const float* __restrict__ scores,
                         const int* __restrict__ labels, const float* __restrict__ reg,
                         const float* __restrict__ asz, const int* __restrict__ pW,
                         int M, int A,
                         float* __restrict__ sel_score, int* __restrict__ sel_label,
                         float* __restrict__ boxes, float* __restrict__ areas,
                         float* __restrict__ obox) {
  __shared__ unsigned hist[4096];
  __shared__ unsigned chunks[1024];
  __shared__ unsigned long long cand[CAND_CAP];
  __shared__ int sB1, sB2;
  __shared__ unsigned sAbove, scnt;
  const int t = threadIdx.x;
  const int M4 = M >> 2;
  const float4* s4 = reinterpret_cast<const float4*>(scores);

  #pragma unroll
  for (int k = 0; k < 4; ++k) hist[t + 1024 * k] = 0u;
  if (t == 0) scnt = 0u;
  __syncthreads();

  // ---- Scan 1: 4096-bin hist on key bits [31:20] ----
  for (int i = t; i < M4; i += 1024) {
    float4 v = s4[i];
    agg_add(hist, fkey(v.x) >> 20, true);
    agg_add(hist, fkey(v.y) >> 20, true);
    agg_add(hist, fkey(v.z) >> 20, true);
    agg_add(hist, fkey(v.w) >> 20, true);
  }
  __syncthreads();
  chunks[t] = hist[4 * t] + hist[4 * t + 1] + hist[4 * t + 2] + hist[4 * t + 3];
  __syncthreads();
  for (int d = 1; d < 1024; d <<= 1) {   // inclusive suffix sum
    unsigned v = chunks[t] + ((t + d < 1024) ? chunks[t + d] : 0u);
    __syncthreads();
    chunks[t] = v;
    __syncthreads();
  }
  {
    unsigned ssc = chunks[t];
    unsigned ssn = (t + 1 < 1024) ? chunks[t + 1] : 0u;
    if (ssc >= (unsigned)TOPK && ssn < (unsigned)TOPK) {
      unsigned run = ssn;
      for (int b = 3; b >= 0; --b) {
        unsigned h = hist[4 * t + b];
        run += h;
        if (run >= (unsigned)TOPK) { sB1 = 4 * t + b; sAbove = run - h; break; }
      }
    }
  }
  __syncthreads();
  const unsigned B1 = (unsigned)sB1;
  const unsigned nAb = sAbove;
  #pragma unroll
  for (int k = 0; k < 4; ++k) hist[t + 1024 * k] = 0u;
  __syncthreads();

  // ---- Scan 2: 4096-bin hist on key bits [19:8] within bin B1 ----
  for (int i = t; i < M4; i += 1024) {
    float4 v = s4[i];
    unsigned k0 = fkey(v.x), k1 = fkey(v.y), k2 = fkey(v.z), k3 = fkey(v.w);
    agg_add(hist, (k0 >> 8) & 0xFFFu, (k0 >> 20) == B1);
    agg_add(hist, (k1 >> 8) & 0xFFFu, (k1 >> 20) == B1);
    agg_add(hist, (k2 >> 8) & 0xFFFu, (k2 >> 20) == B1);
    agg_add(hist, (k3 >> 8) & 0xFFFu, (k3 >> 20) == B1);
  }
  __syncthreads();
  chunks[t] = hist[4 * t] + hist[4 * t + 1] + hist[4 * t + 2] + hist[4 * t + 3];
  __syncthreads();
  for (int d = 1; d < 1024; d <<= 1) {
    unsigned v = chunks[t] + ((t + d < 1024) ? chunks[t + d] : 0u);
    __syncthreads();
    chunks[t] = v;
    __syncthreads();
  }
  {
    unsigned ssc = nAb + chunks[t];
    unsigned ssn = nAb + ((t + 1 < 1024) ? chunks[t + 1] : 0u);
    if (ssc >= (unsigned)TOPK && ssn < (unsigned)TOPK) {
      unsigned run = ssn;
      for (int b = 3; b >= 0; --b) {
        run += hist[4 * t + b];
        if (run >= (unsigned)TOPK) { sB2 = 4 * t + b; break; }
      }
    }
  }
  __syncthreads();
  const unsigned T = (B1 << 20) | ((unsigned)sB2 << 8);

  // ---- Scan 3: compact keys >= T (24-bit threshold), aggregated append ----
  for (int i = t; i < M; i += 1024) {
    unsigned key = fkey(scores[i]);
    bool pred = key >= T;
    unsigned long long m = __ballot(pred);
    if (m) {
      int lane = t & 63;
      int leader = __ffsll(m) - 1;
      unsigned base = 0;
      if (lane == leader) base = atomicAdd(&scnt, (unsigned)__popcll(m));
      base = (unsigned)__shfl((int)base, leader, 64);
      if (pred) {
        unsigned p = base + (unsigned)__popcll(m & ((1ull << lane) - 1ull));
        if (p < (unsigned)CAND_CAP)
          cand[p] = ((unsigned long long)key << 32) | (unsigned)(~(unsigned)i);
      }
    }
  }
  __syncthreads();
  unsigned n = scnt; if (n > (unsigned)CAND_CAP) n = (unsigned)CAND_CAP;
  for (int i = t; i < CAND_CAP; i += 1024) if ((unsigned)i >= n) cand[i] = 0ull;
  __syncthreads();

  // ---- bitonic sort (descending), 2048 elems, 1 compare/thread/step ----
  for (int k = 2; k <= CAND_CAP; k <<= 1) {
    for (int j = k >> 1; j > 0; j >>= 1) {
      int i = ((t & ~(j - 1)) << 1) | (t & (j - 1));
      int ij = i | j;
      unsigned long long a = cand[i], b = cand[ij];
      bool desc = (i & k) == 0;
      if ((a < b) == desc) { cand[i] = b; cand[ij] = a; }
      __syncthreads();
    }
  }

  // ---- decode top-1000 ----
  if (t < TOPK) {
    unsigned long long kk = cand[t];
    unsigned key = (unsigned)(kk >> 32);
    unsigned u = (key & 0x80000000u) ? (key ^ 0x80000000u) : ~key;
    float sc = __uint_as_float(u);
    int idx = (int)(~(unsigned)kk);
    int lab = labels[idx];
    int W = *pW;
    int a = idx % A;
    int cell = idx / A;
    int x = cell % W;
    int y = cell / W;
    float aw = asz[a * 2 + 0], ah = asz[a * 2 + 1];
    float ax = ((float)x + 0.5f) * 32.0f;
    float ay = ((float)y + 0.5f) * 32.0f;
    float4 rg = *reinterpret_cast<const float4*>(reg + (size_t)idx * 4);
    float offx = fminf(fmaxf(rg.x * aw, -32.0f), 32.0f);
    float offy = fminf(fmaxf(rg.y * ah, -32.0f), 32.0f);
    float cx = ax + offx, cy = ay + offy;
    const float SC = 4.135166556742356f;  // log(1000/16)
    float bw = aw * exp_np(fminf(rg.z, SC));
    float bh = ah * exp_np(fminf(rg.w, SC));
    float x1 = cx - 0.5f * bw, y1 = cy - 0.5f * bh;
    float x2 = cx + 0.5f * bw, y2 = cy + 0.5f * bh;
    float off = (float)lab * 100000.0f;
    float ox1 = x1 + off, oy1 = y1 + off, ox2 = x2 + off, oy2 = y2 + off;
    sel_score[t] = sc; sel_label[t] = lab;
    boxes[t * 4 + 0] = x1; boxes[t * 4 + 1] = y1;
    boxes[t * 4 + 2] = x2; boxes[t * 4 + 3] = y2;
    obox[0 * 1024 + t] = ox1; obox[1 * 1024 + t] = oy1;
    obox[2 * 1024 + t] = ox2; obox[3 * 1024 + t] = oy2;
    areas[t] = (ox2 - ox1) * (oy2 - oy1);  // areas on offset boxes, like the reference
  }
}

// Block-uniform word index wq; boxes staged in LDS (same-address broadcast reads).
// Mask stored TRANSPOSED: maskT[wq*1024 + i] (coalesced store, coalesced load).
__launch_bounds__(256)
__global__ void k_mask(const float* __restrict__ obox, const float* __restrict__ areas,
                       unsigned long long* __restrict__ maskT) {
  __shared__ float so0[1024], so1[1024], so2[1024], so3[1024], sa[1024];
  const int t = threadIdx.x;
  int g = blockIdx.x * 256 + t;
  int wq = g >> 10, i = g & 1023;
  for (int idx = t; idx < 1024; idx += 256) {
    so0[idx] = obox[idx];        so1[idx] = obox[1024 + idx];
    so2[idx] = obox[2048 + idx]; so3[idx] = obox[3072 + idx];
    sa[idx] = areas[idx];
  }
  __syncthreads();
  if (i >= TOPK) return;
  float x1i = so0[i], y1i = so1[i], x2i = so2[i], y2i = so3[i];
  float ai = sa[i];
  unsigned long long bits = 0ull;
  int j0 = wq * 64;
  for (int jj = 0; jj < 64; ++jj) {
    int j = j0 + jj;                       // block-uniform: LDS broadcast
    if (j < TOPK && j > i) {
      float xx1 = fmaxf(x1i, so0[j]);
      float yy1 = fmaxf(y1i, so1[j]);
      float xx2 = fminf(x2i, so2[j]);
      float yy2 = fminf(y2i, so3[j]);
      float inter = fmaxf(1e-28f, xx2 - xx1) * fmaxf(1e-28f, yy2 - yy1);
      float uni = ai + sa[j] - inter + 1e-14f;
      float iou = inter / uni;             // IEEE division: bit-matches reference
      if (iou > 0.6f) bits |= (1ull << jj);
    }
  }
  maskT[wq * 1024 + i] = bits;
}

__device__ __forceinline__ unsigned long long shfl64(unsigned long long v, int src) {
  unsigned lo = (unsigned)__shfl((int)(unsigned)(v & 0xffffffffull), src, 64);
  unsigned hi = (unsigned)__shfl((int)(unsigned)(v >> 32), src, 64);
  return ((unsigned long long)hi << 32) | lo;
}

__launch_bounds__(1024)
__global__ void k_nms_out(const unsigned long long* __restrict__ maskT,
                          const float* __restrict__ sel_score, const int* __restrict__ sel_label,
                          const float* __restrict__ boxes,
                          const int* __restrict__ pW, const int* __restrict__ pH,
                          float* __restrict__ out) {
  __shared__ unsigned long long mT[NWORDS * 1025];  // padded: lanes 0..15 -> 16 banks
  __shared__ unsigned long long validw[NWORDS];
  __shared__ unsigned long long keepw[NWORDS];
  const int t = threadIdx.x;
  for (int idx = t; idx < NWORDS * 1024; idx += 1024)
    mT[(idx >> 10) * 1025 + (idx & 1023)] = maskT[idx];
  if (t < NWORDS) {
    unsigned long long v = 0ull;
    for (int b = 0; b < 64; ++b) {
      int r = t * 64 + b;
      if (r < TOPK && sel_score[r] >= 0.05f) v |= (1ull << b);
    }
    validw[t] = v;
  }
  __syncthreads();

  if (t < 64) {  // wave 0: serial greedy; broadcast words prefetched from LDS
    const int lane = t;
    unsigned long long supp = 0ull, kw = 0ull;
    unsigned long long cur_supp = 0ull, cur_valid = 0ull;
    unsigned long long bufA[8], bufW[8], nbufA[8], nbufW[8];
    #pragma unroll
    for (int k = 0; k < 8; ++k) {
      bufA[k] = (lane < NWORDS) ? mT[lane * 1025 + k] : 0ull;
      bufW[k] = mT[(k >> 6) * 1025 + k];  // same-addr broadcast
    }
    for (int g = 0; g < TOPK / 8; ++g) {
      int gn = g + 1;
      #pragma unroll
      for (int k = 0; k < 8; ++k) {
        int i2 = gn * 8 + k;
        bool ok = gn < TOPK / 8;
        nbufA[k] = (ok && lane < NWORDS) ? mT[lane * 1025 + i2] : 0ull;
        nbufW[k] = ok ? mT[(i2 >> 6) * 1025 + i2] : 0ull;
      }
      #pragma unroll
      for (int k = 0; k < 8; ++k) {
        int i = g * 8 + k;
        int wi = i >> 6, bit = i & 63;
        if (bit == 0) { cur_supp = shfl64(supp, wi); cur_valid = validw[wi]; }
        bool kept = ((cur_valid >> bit) & 1ull) && !((cur_supp >> bit) & 1ull);
        if (kept) {
          cur_supp |= bufW[k];      // replicated copy: chain stays register-local
          supp |= bufA[k];          // distributed OR (lanes 0..15 matter)
          if (lane == wi) kw |= (1ull << bit);
        }
      }
      #pragma unroll
      for (int k = 0; k < 8; ++k) { bufA[k] = nbufA[k]; bufW[k] = nbufW[k]; }
    }
    if (lane < NWORDS) keepw[lane] = kw;
  }
  __syncthreads();

  if (t < TOPK) {
    bool kp = (keepw[t >> 6] >> (t & 63)) & 1ull;
    float m = kp ? 1.0f : 0.0f;
    float sw = (float)(*pW * 32);
    float sh = (float)(*pH * 32);
    float b0 = boxes[t * 4 + 0] / sw;
    float b1 = boxes[t * 4 + 1] / sh;
    float b2 = boxes[t * 4 + 2] / sw;
    float b3 = boxes[t * 4 + 3] / sh;
    b0 = fminf(fmaxf(b0, 0.0f), 1.0f) * m;
    b1 = fminf(fmaxf(b1, 0.0f), 1.0f) * m;
    b2 = fminf(fmaxf(b2, 0.0f), 1.0f) * m;
    b3 = fminf(fmaxf(b3, 0.0f), 1.0f) * m;
    out[t * 4 + 0] = b0; out[t * 4 + 1] = b1;
    out[t * 4 + 2] = b2; out[t * 4 + 3] = b3;
    out[TOPK * 4 + t] = sel_score[t] * m;
    out[TOPK * 5 + t] = kp ? (float)sel_label[t] : -1.0f;
    out[TOPK * 6 + t] = m;
  }
}

extern "C" void kernel_launch(void* const* d_in, const int* in_sizes, int n_in,
                              void* d_out, int out_size, void* d_ws, size_t ws_size,
                              hipStream_t stream) {
  const float* cls = (const float*)d_in[0];
  const float* reg = (const float*)d_in[1];
  const float* asz = (const float*)d_in[2];
  const int* pH = (const int*)d_in[3];
  const int* pW = (const int*)d_in[4];
  int M = in_sizes[0] / NCLS;
  int A = in_sizes[2] / 2;

  char* ws = (char*)d_ws;
  size_t off = 0;
  auto alloc = [&](size_t bytes) { size_t o = off; off = (off + bytes + 255) & ~(size_t)255; return o; };
  size_t o_sc    = alloc((size_t)M * sizeof(float));
  size_t o_lb    = alloc((size_t)M * sizeof(int));
  size_t o_ssc   = alloc(1024 * sizeof(float));
  size_t o_slb   = alloc(1024 * sizeof(int));
  size_t o_box   = alloc((size_t)TOPK * 4 * sizeof(float));
  size_t o_area  = alloc(1024 * sizeof(float));
  size_t o_obox  = alloc(4 * 1024 * sizeof(float));
  size_t o_mask  = alloc((size_t)NWORDS * 1024 * sizeof(unsigned long long));
  (void)ws_size; (void)out_size; (void)n_in;

  int nthread = M * 4;
  k_score<<<(nthread + 255) / 256, 256, 0, stream>>>(
      cls, (float*)(ws + o_sc), (int*)(ws + o_lb), M);
  k_select<<<1, 1024, 0, stream>>>(
      (const float*)(ws + o_sc), (const int*)(ws + o_lb),
      reg, asz, pW, M, A,
      (float*)(ws + o_ssc), (int*)(ws + o_slb),
      (float*)(ws + o_box), (float*)(ws + o_area), (float*)(ws + o_obox));
  k_mask<<<(NWORDS * 1024) / 256, 256, 0, stream>>>(
      (const float*)(ws + o_obox), (const float*)(ws + o_area),
      (unsigned long long*)(ws + o_mask));
  k_nms_out<<<1, 1024, 0, stream>>>(
      (const unsigned long long*)(ws + o_mask),
      (const float*)(ws + o_ssc), (const int*)(ws + o_slb),
      (const float*)(ws + o_box), pW, pH, (float*)d_out);
}

// Round 4
// 149.395 us; speedup vs baseline: 2.1642x; 1.6235x over previous
//
#include <hip/hip_runtime.h>
#include <math.h>

#define NCLS 80
#define TOPK 1000
#define NWORDS 16          // ceil(1000/64)
#define CAND_CAP 4096

// Correctly-rounded float sigmoid: matches numpy's 1/(1+np.exp(-x)) bit-for-bit.
__device__ __forceinline__ float sigmoid_np(float x) {
  float e = (float)exp(-(double)x);
  return 1.0f / (1.0f + e);
}
__device__ __forceinline__ float exp_np(float x) { return (float)exp((double)x); }

// monotonic float->uint key
__device__ __forceinline__ unsigned fkey(float s) {
  unsigned u = __float_as_uint(s);
  return ((int)u < 0) ? ~u : (u | 0x80000000u);
}

// Wave-aggregated LDS histogram add: one atomic per distinct bin per wave.
__device__ __forceinline__ void agg_add(unsigned* h, unsigned bin, bool pred) {
  unsigned long long rem = __ballot(pred);
  const int lane = threadIdx.x & 63;
  while (rem) {
    int leader = __ffsll(rem) - 1;
    unsigned lb = (unsigned)__shfl((int)bin, leader, 64);
    unsigned long long m = __ballot(pred && bin == lb);
    if (lane == leader) atomicAdd(&h[lb], (unsigned)__popcll(m));
    rem &= ~m;
  }
}

// 4 lanes per anchor; argmax on raw logits; one exact sigmoid per anchor;
// fused per-block LDS histogram of key[31:20] merged to ghist1 (nonzero bins only).
__launch_bounds__(1024)
__global__ void k_score(const float* __restrict__ cls, float* __restrict__ scores,
                        int* __restrict__ labels, unsigned* __restrict__ ghist1, int M) {
  __shared__ unsigned h1[4096];
  const int t = threadIdx.x;
  #pragma unroll
  for (int k = 0; k < 4; ++k) h1[t + 1024 * k] = 0u;
  __syncthreads();

  int gid = blockIdx.x * 1024 + t;
  int anchor = gid >> 2;
  int q = gid & 3;
  bool act = anchor < M;
  float lv[20];
  float best = -3.4e38f; int bc = 0;
  if (act) {
    const float4* row = reinterpret_cast<const float4*>(cls) + (size_t)anchor * (NCLS / 4);
    #pragma unroll
    for (int k = 0; k < 5; ++k) {
      float4 v = row[q + 4 * k];
      int cbase = (q + 4 * k) * 4;
      lv[4 * k + 0] = v.x; lv[4 * k + 1] = v.y; lv[4 * k + 2] = v.z; lv[4 * k + 3] = v.w;
      if (v.x > best) { best = v.x; bc = cbase + 0; }
      if (v.y > best) { best = v.y; bc = cbase + 1; }
      if (v.z > best) { best = v.z; bc = cbase + 2; }
      if (v.w > best) { best = v.w; bc = cbase + 3; }
    }
  } else {
    #pragma unroll
    for (int k = 0; k < 20; ++k) lv[k] = -3.4e38f;
  }
  #pragma unroll
  for (int d = 1; d < 4; d <<= 1) {
    float ob = __shfl_xor(best, d, 64);
    int oc = __shfl_xor(bc, d, 64);
    if (ob > best || (ob == best && oc < bc)) { best = ob; bc = oc; }
  }
  float s = sigmoid_np(best);
  // collision band: logit gap below this can round to the same float sigmoid
  float sp = s * (1.0f - s);
  float band = (s < 1.0f && sp > 0.0f) ? (4.8e-7f / sp) : 3.4e38f;  // 8 ulps margin
  float thresh = best - band;
  int cclose = 1 << 30;
  #pragma unroll
  for (int k = 0; k < 5; ++k) {
    #pragma unroll
    for (int j = 0; j < 4; ++j) {
      int c = (q + 4 * k) * 4 + j;
      if (lv[4 * k + j] >= thresh && c < cclose) cclose = c;
    }
  }
  #pragma unroll
  for (int d = 1; d < 4; d <<= 1) {
    int oc = __shfl_xor(cclose, d, 64);
    if (oc < cclose) cclose = oc;
  }
  int lab = bc;
  if (act && cclose < bc && q == 0) {  // rare: exact serial argmax over rounded sigmoids
    float bp = -1.0f; int bl = 0;
    for (int c = 0; c < NCLS; ++c) {
      float p = sigmoid_np(cls[(size_t)anchor * NCLS + c]);
      if (p > bp) { bp = p; bl = c; }
    }
    lab = bl;
  }
  if (act && q == 0) {
    scores[anchor] = s;
    labels[anchor] = lab;
  }
  agg_add(h1, fkey(s) >> 20, act && q == 0);
  __syncthreads();
  #pragma unroll
  for (int k = 0; k < 4; ++k) {
    unsigned c = h1[t + 1024 * k];
    if (c) atomicAdd(&ghist1[t + 1024 * k], c);
  }
}

// Each block recomputes B1 (coarse threshold bin) from ghist1, then histograms
// key bits [19:8] of elements in bin B1 into global ghist2. Block 0 stores meta.
__launch_bounds__(1024)
__global__ void k_hist2(const unsigned* __restrict__ ghist1, const float* __restrict__ scores,
                        unsigned* __restrict__ ghist2, unsigned* __restrict__ gmeta, int M) {
  __shared__ unsigned chunks[1024];
  __shared__ int sB1; __shared__ unsigned sAb;
  const int t = threadIdx.x;
  unsigned hb0 = ghist1[4 * t], hb1 = ghist1[4 * t + 1],
           hb2 = ghist1[4 * t + 2], hb3 = ghist1[4 * t + 3];
  chunks[t] = hb0 + hb1 + hb2 + hb3;
  __syncthreads();
  for (int d = 1; d < 1024; d <<= 1) {   // inclusive suffix sum
    unsigned v = chunks[t] + ((t + d < 1024) ? chunks[t + d] : 0u);
    __syncthreads();
    chunks[t] = v;
    __syncthreads();
  }
  {
    unsigned ssc = chunks[t];
    unsigned ssn = (t + 1 < 1024) ? chunks[t + 1] : 0u;
    if (ssc >= (unsigned)TOPK && ssn < (unsigned)TOPK) {
      unsigned hb[4] = {hb0, hb1, hb2, hb3};
      unsigned run = ssn;
      for (int b = 3; b >= 0; --b) {
        run += hb[b];
        if (run >= (unsigned)TOPK) { sB1 = 4 * t + b; sAb = run - hb[b]; break; }
      }
    }
  }
  __syncthreads();
  const unsigned B1 = (unsigned)sB1;
  if (blockIdx.x == 0 && t == 0) { gmeta[0] = B1; gmeta[1] = sAb; }

  int base = (blockIdx.x * 1024 + t) * 4;
  if (base + 3 < M) {
    float4 v = *reinterpret_cast<const float4*>(scores + base);
    unsigned k0 = fkey(v.x), k1 = fkey(v.y), k2 = fkey(v.z), k3 = fkey(v.w);
    if ((k0 >> 20) == B1) atomicAdd(&ghist2[(k0 >> 8) & 0xFFFu], 1u);
    if ((k1 >> 20) == B1) atomicAdd(&ghist2[(k1 >> 8) & 0xFFFu], 1u);
    if ((k2 >> 20) == B1) atomicAdd(&ghist2[(k2 >> 8) & 0xFFFu], 1u);
    if ((k3 >> 20) == B1) atomicAdd(&ghist2[(k3 >> 8) & 0xFFFu], 1u);
  } else {
    for (int j = base; j < M; ++j) {
      unsigned k0 = fkey(scores[j]);
      if ((k0 >> 20) == B1) atomicAdd(&ghist2[(k0 >> 8) & 0xFFFu], 1u);
    }
  }
}

// Each block recomputes the 24-bit threshold T from ghist2+meta, then compacts
// its slice of keys >= T into the global candidate buffer (1 atomic per block).
__launch_bounds__(1024)
__global__ void k_compact(const unsigned* __restrict__ ghist2, const unsigned* __restrict__ gmeta,
                          const float* __restrict__ scores,
                          unsigned long long* __restrict__ cand, unsigned* __restrict__ gcount,
                          int M) {
  __shared__ unsigned chunks[1024];
  __shared__ int sB2;
  __shared__ unsigned wcnt[16];
  __shared__ unsigned sbase;
  const int t = threadIdx.x;
  const unsigned B1 = gmeta[0], nAb = gmeta[1];
  unsigned hb0 = ghist2[4 * t], hb1 = ghist2[4 * t + 1],
           hb2 = ghist2[4 * t + 2], hb3 = ghist2[4 * t + 3];
  chunks[t] = hb0 + hb1 + hb2 + hb3;
  __syncthreads();
  for (int d = 1; d < 1024; d <<= 1) {
    unsigned v = chunks[t] + ((t + d < 1024) ? chunks[t + d] : 0u);
    __syncthreads();
    chunks[t] = v;
    __syncthreads();
  }
  {
    unsigned ssc = nAb + chunks[t];
    unsigned ssn = nAb + ((t + 1 < 1024) ? chunks[t + 1] : 0u);
    if (ssc >= (unsigned)TOPK && ssn < (unsigned)TOPK) {
      unsigned hb[4] = {hb0, hb1, hb2, hb3};
      unsigned run = ssn;
      for (int b = 3; b >= 0; --b) {
        run += hb[b];
        if (run >= (unsigned)TOPK) { sB2 = 4 * t + b; break; }
      }
    }
  }
  __syncthreads();
  const unsigned T = (B1 << 20) | ((unsigned)sB2 << 8);

  int base = (blockIdx.x * 1024 + t) * 4;
  unsigned keys[4]; int idxs[4]; int np = 0;
  #pragma unroll
  for (int j = 0; j < 4; ++j) {
    int i = base + j;
    if (i < M) {
      unsigned key = fkey(scores[i]);
      if (key >= T) { keys[np] = key; idxs[np] = i; ++np; }
    }
  }
  // wave inclusive scan of np
  const int lane = t & 63, wid = t >> 6;
  int sc = np;
  #pragma unroll
  for (int d = 1; d < 64; d <<= 1) {
    int o = __shfl_up(sc, d, 64);
    if (lane >= d) sc += o;
  }
  if (lane == 63) wcnt[wid] = (unsigned)sc;
  __syncthreads();
  if (t == 0) {
    unsigned acc = 0;
    for (int w = 0; w < 16; ++w) { unsigned v = wcnt[w]; wcnt[w] = acc; acc += v; }
    sbase = acc ? atomicAdd(gcount, acc) : 0u;
  }
  __syncthreads();
  unsigned pos = sbase + wcnt[wid] + (unsigned)(sc - np);
  for (int j = 0; j < np; ++j) {
    if (pos < (unsigned)CAND_CAP)
      cand[pos] = ((unsigned long long)keys[j] << 32) | (unsigned)(~(unsigned)idxs[j]);
    ++pos;
  }
}

// Exact rank (N^2 over <=CAND_CAP distinct keys) + decode, one block.
__launch_bounds__(1024)
__global__ void k_rank(const unsigned long long* __restrict__ cand, const unsigned* __restrict__ gcount,
                       const int* __restrict__ labels, const float* __restrict__ reg,
                       const float* __restrict__ asz, const int* __restrict__ pW, int A,
                       float* __restrict__ sel_score, int* __restrict__ sel_label,
                       float* __restrict__ boxes, float* __restrict__ areas,
                       float* __restrict__ obox) {
  __shared__ unsigned long long ck[CAND_CAP];  // 32KB
  const int t = threadIdx.x;
  unsigned n = *gcount; if (n > (unsigned)CAND_CAP) n = (unsigned)CAND_CAP;
  for (int i = t; i < CAND_CAP; i += 1024) ck[i] = (i < (int)n) ? cand[i] : 0ull;
  __syncthreads();
  for (int c = t; c < (int)n; c += 1024) {
    unsigned long long my = ck[c];
    int r = 0;
    for (int j = 0; j < (int)n; ++j) r += (ck[j] > my);   // uniform j: LDS broadcast
    if (r < TOPK) {
      unsigned key = (unsigned)(my >> 32);
      unsigned u = (key & 0x80000000u) ? (key ^ 0x80000000u) : ~key;
      float scv = __uint_as_float(u);
      int idx = (int)(~(unsigned)my);
      int lab = labels[idx];
      int W = *pW;
      int a = idx % A;
      int cell = idx / A;
      int x = cell % W;
      int y = cell / W;
      float aw = asz[a * 2 + 0], ah = asz[a * 2 + 1];
      float ax = ((float)x + 0.5f) * 32.0f;
      float ay = ((float)y + 0.5f) * 32.0f;
      float4 rg = *reinterpret_cast<const float4*>(reg + (size_t)idx * 4);
      float offx = fminf(fmaxf(rg.x * aw, -32.0f), 32.0f);
      float offy = fminf(fmaxf(rg.y * ah, -32.0f), 32.0f);
      float cx = ax + offx, cy = ay + offy;
      const float SC = 4.135166556742356f;  // log(1000/16)
      float bw = aw * exp_np(fminf(rg.z, SC));
      float bh = ah * exp_np(fminf(rg.w, SC));
      float x1 = cx - 0.5f * bw, y1 = cy - 0.5f * bh;
      float x2 = cx + 0.5f * bw, y2 = cy + 0.5f * bh;
      float off = (float)lab * 100000.0f;
      float ox1 = x1 + off, oy1 = y1 + off, ox2 = x2 + off, oy2 = y2 + off;
      sel_score[r] = scv; sel_label[r] = lab;
      boxes[r * 4 + 0] = x1; boxes[r * 4 + 1] = y1;
      boxes[r * 4 + 2] = x2; boxes[r * 4 + 3] = y2;
      obox[0 * 1024 + r] = ox1; obox[1 * 1024 + r] = oy1;
      obox[2 * 1024 + r] = ox2; obox[3 * 1024 + r] = oy2;
      areas[r] = (ox2 - ox1) * (oy2 - oy1);  // areas on offset boxes, like the reference
    }
  }
}

// Block-uniform word index wq; boxes staged in LDS (same-address broadcast reads).
// Mask stored TRANSPOSED: maskT[wq*1024 + i].
__launch_bounds__(256)
__global__ void k_mask(const float* __restrict__ obox, const float* __restrict__ areas,
                       unsigned long long* __restrict__ maskT) {
  __shared__ float so0[1024], so1[1024], so2[1024], so3[1024], sa[1024];
  const int t = threadIdx.x;
  int g = blockIdx.x * 256 + t;
  int wq = g >> 10, i = g & 1023;
  for (int idx = t; idx < 1024; idx += 256) {
    so0[idx] = obox[idx];        so1[idx] = obox[1024 + idx];
    so2[idx] = obox[2048 + idx]; so3[idx] = obox[3072 + idx];
    sa[idx] = areas[idx];
  }
  __syncthreads();
  if (i >= TOPK) return;
  float x1i = so0[i], y1i = so1[i], x2i = so2[i], y2i = so3[i];
  float ai = sa[i];
  unsigned long long bits = 0ull;
  int j0 = wq * 64;
  for (int jj = 0; jj < 64; ++jj) {
    int j = j0 + jj;                       // block-uniform: LDS broadcast
    if (j < TOPK && j > i) {
      float xx1 = fmaxf(x1i, so0[j]);
      float yy1 = fmaxf(y1i, so1[j]);
      float xx2 = fminf(x2i, so2[j]);
      float yy2 = fminf(y2i, so3[j]);
      float inter = fmaxf(1e-28f, xx2 - xx1) * fmaxf(1e-28f, yy2 - yy1);
      float uni = ai + sa[j] - inter + 1e-14f;
      float iou = inter / uni;             // IEEE division: bit-matches reference
      if (iou > 0.6f) bits |= (1ull << jj);
    }
  }
  maskT[wq * 1024 + i] = bits;
}

__device__ __forceinline__ unsigned long long shfl64(unsigned long long v, int src) {
  unsigned lo = (unsigned)__shfl((int)(unsigned)(v & 0xffffffffull), src, 64);
  unsigned hi = (unsigned)__shfl((int)(unsigned)(v >> 32), src, 64);
  return ((unsigned long long)hi << 32) | lo;
}

__launch_bounds__(1024)
__global__ void k_nms_out(const unsigned long long* __restrict__ maskT,
                          const float* __restrict__ sel_score, const int* __restrict__ sel_label,
                          const float* __restrict__ boxes,
                          const int* __restrict__ pW, const int* __restrict__ pH,
                          float* __restrict__ out) {
  __shared__ unsigned long long mT[NWORDS * 1025];  // padded: lanes 0..15 -> 16 banks
  __shared__ unsigned long long validw[NWORDS];
  __shared__ unsigned long long keepw[NWORDS];
  const int t = threadIdx.x;
  for (int idx = t; idx < NWORDS * 1024; idx += 1024)
    mT[(idx >> 10) * 1025 + (idx & 1023)] = maskT[idx];
  if (t < NWORDS) {
    unsigned long long v = 0ull;
    for (int b = 0; b < 64; ++b) {
      int r = t * 64 + b;
      if (r < TOPK && sel_score[r] >= 0.05f) v |= (1ull << b);
    }
    validw[t] = v;
  }
  __syncthreads();

  if (t < 64) {  // wave 0: serial greedy; broadcast words prefetched from LDS
    const int lane = t;
    unsigned long long supp = 0ull, kw = 0ull;
    unsigned long long cur_supp = 0ull, cur_valid = 0ull;
    unsigned long long bufA[8], bufW[8], nbufA[8], nbufW[8];
    #pragma unroll
    for (int k = 0; k < 8; ++k) {
      bufA[k] = (lane < NWORDS) ? mT[lane * 1025 + k] : 0ull;
      bufW[k] = mT[(k >> 6) * 1025 + k];  // same-addr broadcast
    }
    for (int g = 0; g < TOPK / 8; ++g) {
      int gn = g + 1;
      #pragma unroll
      for (int k = 0; k < 8; ++k) {
        int i2 = gn * 8 + k;
        bool ok = gn < TOPK / 8;
        nbufA[k] = (ok && lane < NWORDS) ? mT[lane * 1025 + i2] : 0ull;
        nbufW[k] = ok ? mT[(i2 >> 6) * 1025 + i2] : 0ull;
      }
      #pragma unroll
      for (int k = 0; k < 8; ++k) {
        int i = g * 8 + k;
        int wi = i >> 6, bit = i & 63;
        if (bit == 0) { cur_supp = shfl64(supp, wi); cur_valid = validw[wi]; }
        bool kept = ((cur_valid >> bit) & 1ull) && !((cur_supp >> bit) & 1ull);
        if (kept) {
          cur_supp |= bufW[k];      // replicated copy: chain stays register-local
          supp |= bufA[k];          // distributed OR (lanes 0..15 matter)
          if (lane == wi) kw |= (1ull << bit);
        }
      }
      #pragma unroll
      for (int k = 0; k < 8; ++k) { bufA[k] = nbufA[k]; bufW[k] = nbufW[k]; }
    }
    if (lane < NWORDS) keepw[lane] = kw;
  }
  __syncthreads();

  if (t < TOPK) {
    bool kp = (keepw[t >> 6] >> (t & 63)) & 1ull;
    float m = kp ? 1.0f : 0.0f;
    float sw = (float)(*pW * 32);
    float sh = (float)(*pH * 32);
    float b0 = boxes[t * 4 + 0] / sw;
    float b1 = boxes[t * 4 + 1] / sh;
    float b2 = boxes[t * 4 + 2] / sw;
    float b3 = boxes[t * 4 + 3] / sh;
    b0 = fminf(fmaxf(b0, 0.0f), 1.0f) * m;
    b1 = fminf(fmaxf(b1, 0.0f), 1.0f) * m;
    b2 = fminf(fmaxf(b2, 0.0f), 1.0f) * m;
    b3 = fminf(fmaxf(b3, 0.0f), 1.0f) * m;
    out[t * 4 + 0] = b0; out[t * 4 + 1] = b1;
    out[t * 4 + 2] = b2; out[t * 4 + 3] = b3;
    out[TOPK * 4 + t] = sel_score[t] * m;
    out[TOPK * 5 + t] = kp ? (float)sel_label[t] : -1.0f;
    out[TOPK * 6 + t] = m;
  }
}

extern "C" void kernel_launch(void* const* d_in, const int* in_sizes, int n_in,
                              void* d_out, int out_size, void* d_ws, size_t ws_size,
                              hipStream_t stream) {
  const float* cls = (const float*)d_in[0];
  const float* reg = (const float*)d_in[1];
  const float* asz = (const float*)d_in[2];
  const int* pH = (const int*)d_in[3];
  const int* pW = (const int*)d_in[4];
  int M = in_sizes[0] / NCLS;
  int A = in_sizes[2] / 2;

  char* ws = (char*)d_ws;
  size_t off = 0;
  auto alloc = [&](size_t bytes) { size_t o = off; off = (off + bytes + 255) & ~(size_t)255; return o; };
  size_t o_h1    = alloc(4096 * sizeof(unsigned));
  size_t o_h2    = alloc(4096 * sizeof(unsigned));
  size_t o_misc  = alloc(256);                       // gcount @ +0, gmeta @ +8
  size_t zero_end = off;
  size_t o_cand  = alloc((size_t)CAND_CAP * sizeof(unsigned long long));
  size_t o_sc    = alloc((size_t)M * sizeof(float));
  size_t o_lb    = alloc((size_t)M * sizeof(int));
  size_t o_ssc   = alloc(1024 * sizeof(float));
  size_t o_slb   = alloc(1024 * sizeof(int));
  size_t o_box   = alloc((size_t)TOPK * 4 * sizeof(float));
  size_t o_area  = alloc(1024 * sizeof(float));
  size_t o_obox  = alloc(4 * 1024 * sizeof(float));
  size_t o_mask  = alloc((size_t)NWORDS * 1024 * sizeof(unsigned long long));
  (void)ws_size; (void)out_size; (void)n_in;

  hipMemsetAsync(ws, 0, zero_end, stream);   // ghist1 + ghist2 + gcount/gmeta

  int nblk_score = (M * 4 + 1023) / 1024;
  k_score<<<nblk_score, 1024, 0, stream>>>(
      cls, (float*)(ws + o_sc), (int*)(ws + o_lb), (unsigned*)(ws + o_h1), M);

  int nblk_scan = ((M + 3) / 4 + 1023) / 1024;
  k_hist2<<<nblk_scan, 1024, 0, stream>>>(
      (const unsigned*)(ws + o_h1), (const float*)(ws + o_sc),
      (unsigned*)(ws + o_h2), (unsigned*)(ws + o_misc + 8), M);
  k_compact<<<nblk_scan, 1024, 0, stream>>>(
      (const unsigned*)(ws + o_h2), (const unsigned*)(ws + o_misc + 8),
      (const float*)(ws + o_sc),
      (unsigned long long*)(ws + o_cand), (unsigned*)(ws + o_misc), M);
  k_rank<<<1, 1024, 0, stream>>>(
      (const unsigned long long*)(ws + o_cand), (const unsigned*)(ws + o_misc),
      (const int*)(ws + o_lb), reg, asz, pW, A,
      (float*)(ws + o_ssc), (int*)(ws + o_slb),
      (float*)(ws + o_box), (float*)(ws + o_area), (float*)(ws + o_obox));
  k_mask<<<(NWORDS * 1024) / 256, 256, 0, stream>>>(
      (const float*)(ws + o_obox), (const float*)(ws + o_area),
      (unsigned long long*)(ws + o_mask));
  k_nms_out<<<1, 1024, 0, stream>>>(
      (const unsigned long long*)(ws + o_mask),
      (const float*)(ws + o_ssc), (const int*)(ws + o_slb),
      (const float*)(ws + o_box), pW, pH, (float*)d_out);
}